// Round 1
// baseline (390.967 us; speedup 1.0000x reference)
//
#include <hip/hip_runtime.h>

#define BB 32
#define HH 512
#define WW 512
#define HW (HH * WW)
#define NPIX (BB * HH * WW)

#define TILE 64
#define H2 8             // double halo (two chained 9x9 blurs)
#define RG2 80           // staged region rows/cols for m,q
#define RQ2 21           // row stride in float4 quads (84 floats)
#define RS2 84           // row stride in floats

// load 12 consecutive floats (3 quads) from LDS into dst[12]
#define LOADROW12(dst, p4, base)                                              \
    {                                                                         \
        float4 A_ = (p4)[base], B_ = (p4)[(base) + 1], C_ = (p4)[(base) + 2]; \
        (dst)[0] = A_.x; (dst)[1] = A_.y; (dst)[2]  = A_.z; (dst)[3]  = A_.w; \
        (dst)[4] = B_.x; (dst)[5] = B_.y; (dst)[6]  = B_.z; (dst)[7]  = B_.w; \
        (dst)[8] = C_.x; (dst)[9] = C_.y; (dst)[10] = C_.z; (dst)[11] = C_.w; \
    }

// ---------------------------------------------------------------------------
// A: fused moments -> blur(m)=lm -> e -> blur(e) -> sigma, per 64x64 tile.
// LDS: mt/qt 80x84 (m,q over tile+8 halo). lm lives only in registers; e is
// written in place into qt. Writes lm, sg, and a per-block partial sigma sum.
// ---------------------------------------------------------------------------
__global__ __launch_bounds__(256, 3) void k_fused(
    const float* __restrict__ x, const float* __restrict__ kw,
    float* __restrict__ lm, float* __restrict__ sg, float* __restrict__ psums)
{
    __shared__ float mt[RG2 * RS2];
    __shared__ float qt[RG2 * RS2];
    __shared__ float wsum[4];

    const int tx = threadIdx.x, ty = threadIdx.y;     // 16 x 16
    const int tid = ty * 16 + tx;
    const int x0 = blockIdx.x * TILE, y0 = blockIdx.y * TILE;
    const float4* x4 = (const float4*)(x + (size_t)blockIdx.z * HW * 3);

    // ---- P1: channel moments of x into LDS over the 80x80 region ----
    for (int i = tid; i < RG2 * 20; i += 256) {
        int r = i / 20, qd = i - r * 20;
        int gy = y0 + r - H2, gx = x0 + 4 * qd - H2;
        float4 m = make_float4(0.f, 0.f, 0.f, 0.f);
        float4 q = make_float4(0.f, 0.f, 0.f, 0.f);
        if (gy >= 0 && gy < HH && gx >= 0 && gx < WW) {
            int go = (gy * WW + gx) >> 2;
            float4 a = x4[3 * go + 0];
            float4 b = x4[3 * go + 1];
            float4 c = x4[3 * go + 2];
            const float t = 1.f / 3.f;
            m.x = (a.x + a.y + a.z) * t;  q.x = (a.x * a.x + a.y * a.y + a.z * a.z) * t;
            m.y = (a.w + b.x + b.y) * t;  q.y = (a.w * a.w + b.x * b.x + b.y * b.y) * t;
            m.z = (b.z + b.w + c.x) * t;  q.z = (b.z * b.z + b.w * b.w + c.x * c.x) * t;
            m.w = (c.y + c.z + c.w) * t;  q.w = (c.y * c.y + c.z * c.z + c.w * c.w) * t;
        }
        *(float4*)&mt[r * RS2 + 4 * qd] = m;
        *(float4*)&qt[r * RS2 + 4 * qd] = q;
    }
    __syncthreads();

    // ---- P2+P3: blur m -> lm (72x72, sliding 12-row register window);
    //             write lm interior to global; e -> qt in place ----
    const float4* m4t = (const float4*)mt;
    float* lmg = lm + (size_t)blockIdx.z * HW;

#pragma unroll 1
    for (int t = tid; t < 324; t += 256) {            // 18x18 tiles of 4x4
        int tr = t / 18;
        int q0 = t - tr * 18;                         // quad col 0..17
        int r0 = tr * 4;                              // row 0..68 step 4
        float fw[4][12];
#pragma unroll
        for (int j = 0; j < 3; ++j) LOADROW12(fw[j], m4t, (r0 + j) * RQ2 + q0);
        float acc[4][4] = {};
#pragma unroll
        for (int ky = 0; ky < 9; ++ky) {
            LOADROW12(fw[(ky + 3) & 3], m4t, (r0 + ky + 3) * RQ2 + q0);
            float w[9];
#pragma unroll
            for (int kx = 0; kx < 9; ++kx) w[kx] = kw[ky * 9 + kx];
#pragma unroll
            for (int my = 0; my < 4; ++my)
#pragma unroll
                for (int kx = 0; kx < 9; ++kx)
#pragma unroll
                    for (int mx = 0; mx < 4; ++mx)
                        acc[my][mx] = fmaf(w[kx], fw[(my + ky) & 3][mx + kx], acc[my][mx]);
        }
        // fused: e = max(q - lm*(2m - lm), 0) into qt (zero outside image),
        // and global lm write for the central 64x64.
        const int gxb = x0 + 4 * q0 - 4;
        const bool xin = (gxb >= 0) && (gxb < WW);
        const bool wr = (r0 >= 4) && (r0 < 68) && (q0 >= 1) && (q0 < 17);
#pragma unroll
        for (int row = 0; row < 4; ++row) {
            int gy = y0 + r0 + row - 4;
            float4 l = make_float4(acc[row][0], acc[row][1], acc[row][2], acc[row][3]);
            int off = (r0 + row + 4) * RS2 + 4 * q0 + 4;
            float4 mm = *(const float4*)&mt[off];
            float4* qp = (float4*)&qt[off];
            float4 qq = *qp;
            float4 e = make_float4(0.f, 0.f, 0.f, 0.f);
            if (xin && gy >= 0 && gy < HH) {
                e.x = fmaxf(qq.x - l.x * (2.f * mm.x - l.x), 0.f);
                e.y = fmaxf(qq.y - l.y * (2.f * mm.y - l.y), 0.f);
                e.z = fmaxf(qq.z - l.z * (2.f * mm.z - l.z), 0.f);
                e.w = fmaxf(qq.w - l.w * (2.f * mm.w - l.w), 0.f);
            }
            *qp = e;
            if (wr) *(float4*)(lmg + (size_t)gy * WW + gxb) = l;
        }
    }
    __syncthreads();

    // ---- P4: blur e -> sigma (4x4 micro-tile, sliding window), reduce ----
    {
        const float4* q4t = (const float4*)qt;
        const int cb = tx + 1;                        // e cols offset by +4 floats
        float fw[4][12];
#pragma unroll
        for (int j = 0; j < 3; ++j) LOADROW12(fw[j], q4t, (4 * ty + j + 4) * RQ2 + cb);
        float acc[4][4] = {};
#pragma unroll
        for (int ky = 0; ky < 9; ++ky) {
            LOADROW12(fw[(ky + 3) & 3], q4t, (4 * ty + ky + 7) * RQ2 + cb);
            float w[9];
#pragma unroll
            for (int kx = 0; kx < 9; ++kx) w[kx] = kw[ky * 9 + kx];
#pragma unroll
            for (int my = 0; my < 4; ++my)
#pragma unroll
                for (int kx = 0; kx < 9; ++kx)
#pragma unroll
                    for (int mx = 0; mx < 4; ++mx)
                        acc[my][mx] = fmaf(w[kx], fw[(my + ky) & 3][mx + kx], acc[my][mx]);
        }
        float s = 0.f;
        float* dp = sg + (size_t)blockIdx.z * HW + (size_t)(y0 + 4 * ty) * WW + x0 + 4 * tx;
#pragma unroll
        for (int my = 0; my < 4; ++my) {
            float4 o;
            o.x = sqrtf(fmaxf(acc[my][0], 0.f));
            o.y = sqrtf(fmaxf(acc[my][1], 0.f));
            o.z = sqrtf(fmaxf(acc[my][2], 0.f));
            o.w = sqrtf(fmaxf(acc[my][3], 0.f));
            *(float4*)(dp + my * WW) = o;
            s += o.x + o.y + o.z + o.w;
        }
#pragma unroll
        for (int off = 32; off > 0; off >>= 1) s += __shfl_down(s, off);
        if ((tid & 63) == 0) wsum[tid >> 6] = s;
        __syncthreads();
        if (tid == 0)
            psums[blockIdx.z * 64 + blockIdx.y * 8 + blockIdx.x] =
                wsum[0] + wsum[1] + wsum[2] + wsum[3];
    }
}

// ---------------------------------------------------------------------------
// B: out = (x - lm) / max(mean_sigma_b, sigma). Reduces the 64 per-tile
// partial sums per batch in-block (no atomics, no memset needed).
// ---------------------------------------------------------------------------
__global__ __launch_bounds__(256) void k_norm(const float4* __restrict__ x4,
                                              const float4* __restrict__ lm4,
                                              const float4* __restrict__ sg4,
                                              const float* __restrict__ psums,
                                              float4* __restrict__ out4) {
    __shared__ float msh;
    int g = blockIdx.x * 256 + threadIdx.x;
    int b = g >> 16;                                  // g / (HW/4); uniform per block
    float s = 0.f;
    if (threadIdx.x < 64) s = psums[b * 64 + threadIdx.x];
#pragma unroll
    for (int off = 32; off > 0; off >>= 1) s += __shfl_down(s, off);
    if (threadIdx.x == 0) msh = s * (1.f / (float)HW);
    __syncthreads();
    float ms = msh;

    float4 l = lm4[g];
    float4 sv = sg4[g];
    float i0 = 1.f / fmaxf(ms, sv.x);
    float i1 = 1.f / fmaxf(ms, sv.y);
    float i2 = 1.f / fmaxf(ms, sv.z);
    float i3 = 1.f / fmaxf(ms, sv.w);
    float4 a = x4[3 * g + 0];
    float4 bb = x4[3 * g + 1];
    float4 c = x4[3 * g + 2];
    float4 o0, o1, o2;
    o0.x = (a.x - l.x) * i0;  o0.y = (a.y - l.x) * i0;  o0.z = (a.z - l.x) * i0;
    o0.w = (a.w - l.y) * i1;  o1.x = (bb.x - l.y) * i1; o1.y = (bb.y - l.y) * i1;
    o1.z = (bb.z - l.z) * i2; o1.w = (bb.w - l.z) * i2; o2.x = (c.x - l.z) * i2;
    o2.y = (c.y - l.w) * i3;  o2.z = (c.z - l.w) * i3;  o2.w = (c.w - l.w) * i3;
    out4[3 * g + 0] = o0;
    out4[3 * g + 1] = o1;
    out4[3 * g + 2] = o2;
}

extern "C" void kernel_launch(void* const* d_in, const int* in_sizes, int n_in,
                              void* d_out, int out_size, void* d_ws, size_t ws_size,
                              hipStream_t stream) {
    const float* x = (const float*)d_in[0];
    const float* kw = (const float*)d_in[1];
    float* out = (float*)d_out;
    float* wsp = (float*)d_ws;
    float* lmb = wsp;                                 // NPIX floats
    float* sgb = wsp + (size_t)NPIX;                  // NPIX floats
    float* ps  = wsp + 2 * (size_t)NPIX;              // 2048 floats

    dim3 blk(16, 16);
    dim3 grd(WW / TILE, HH / TILE, BB);
    k_fused<<<grd, blk, 0, stream>>>(x, kw, lmb, sgb, ps);

    k_norm<<<NPIX / 4 / 256, 256, 0, stream>>>((const float4*)x, (const float4*)lmb,
                                               (const float4*)sgb, ps, (float4*)out);
}

// Round 2
// 260.783 us; speedup vs baseline: 1.4992x; 1.4992x over previous
//
#include <hip/hip_runtime.h>

#define BB 32
#define HH 512
#define WW 512
#define HW (HH * WW)
#define NPIX (BB * HH * WW)

#define TILE 64
#define RG 72            // region rows/cols = TILE + 2*4
#define RQ 19            // row stride in float4 quads (odd -> pad col)
#define RS 76            // row stride in floats
#define NQ (RG * 18)     // 1296 live quads per region

// load 12 consecutive floats (3 quads) from LDS into dst[12]
#define LOADROW12(dst, p4, base)                                              \
    {                                                                         \
        float4 A_ = (p4)[base], B_ = (p4)[(base) + 1], C_ = (p4)[(base) + 2]; \
        (dst)[0] = A_.x; (dst)[1] = A_.y; (dst)[2]  = A_.z; (dst)[3]  = A_.w; \
        (dst)[4] = B_.x; (dst)[5] = B_.y; (dst)[6]  = B_.z; (dst)[7]  = B_.w; \
        (dst)[8] = C_.x; (dst)[9] = C_.y; (dst)[10] = C_.z; (dst)[11] = C_.w; \
    }

// 9x9 blur of the staged region into acc[4][4] per thread.
// Thread (tx,ty) produces output rows 4ty..4ty+3, cols 4tx..4tx+3.
// Sliding 12-row register window; all indices compile-time after unroll.
// Lanes' 8-groups read 8 consecutive quads of one row -> conflict-free.
#define BLUR_4x4(acc, t4, kw, tx, ty)                                         \
    float fw[4][12];                                                          \
    _Pragma("unroll")                                                         \
    for (int j = 0; j < 3; ++j) LOADROW12(fw[j], t4, (4 * (ty) + j) * RQ + (tx)); \
    _Pragma("unroll")                                                         \
    for (int ky = 0; ky < 9; ++ky) {                                          \
        LOADROW12(fw[(ky + 3) & 3], t4, (4 * (ty) + ky + 3) * RQ + (tx));     \
        float w[9];                                                           \
        _Pragma("unroll")                                                     \
        for (int kx = 0; kx < 9; ++kx) w[kx] = kw[ky * 9 + kx];               \
        _Pragma("unroll")                                                     \
        for (int my = 0; my < 4; ++my)                                        \
            _Pragma("unroll")                                                 \
            for (int kx = 0; kx < 9; ++kx)                                    \
                _Pragma("unroll")                                             \
                for (int mx = 0; mx < 4; ++mx)                                \
                    acc[my][mx] = fmaf(w[kx], fw[(my + ky) & 3][mx + kx], acc[my][mx]); \
    }

// ---------------------------------------------------------------------------
// KA: stage m (channel mean of x, computed on the fly) -> blur -> lm.
// m never touches HBM. LDS ~21.9 KB -> ~7 blocks/CU.
// ---------------------------------------------------------------------------
__global__ __launch_bounds__(256) void k_lm(const float* __restrict__ x,
                                            const float* __restrict__ kw,
                                            float* __restrict__ lm) {
    __shared__ float mt[RG * RS];
    const int tx = threadIdx.x, ty = threadIdx.y;     // 16 x 16
    const int tid = ty * 16 + tx;
    const int x0 = blockIdx.x * TILE, y0 = blockIdx.y * TILE;
    const float4* x4 = (const float4*)(x + (size_t)blockIdx.z * HW * 3);

    for (int i = tid; i < NQ; i += 256) {
        int r = i / 18, q = i - r * 18;
        int gy = y0 + r - 4, gx = x0 + 4 * q - 4;
        float4 m = make_float4(0.f, 0.f, 0.f, 0.f);
        if (gy >= 0 && gy < HH && gx >= 0 && gx < WW) {
            int go = (gy * WW + gx) >> 2;
            float4 a = x4[3 * go + 0];
            float4 b = x4[3 * go + 1];
            float4 c = x4[3 * go + 2];
            const float t = 1.f / 3.f;
            m.x = (a.x + a.y + a.z) * t;
            m.y = (a.w + b.x + b.y) * t;
            m.z = (b.z + b.w + c.x) * t;
            m.w = (c.y + c.z + c.w) * t;
        }
        *(float4*)&mt[r * RS + 4 * q] = m;
    }
    __syncthreads();

    const float4* t4 = (const float4*)mt;
    float acc[4][4] = {};
    BLUR_4x4(acc, t4, kw, tx, ty);

    float* dp = lm + (size_t)blockIdx.z * HW + (size_t)(y0 + 4 * ty) * WW + x0 + 4 * tx;
#pragma unroll
    for (int my = 0; my < 4; ++my)
        *(float4*)(dp + my * WW) = make_float4(acc[my][0], acc[my][1], acc[my][2], acc[my][3]);
}

// ---------------------------------------------------------------------------
// KB: stage e = max(q - lm*(2m - lm), 0) directly (x + global lm, moments
// recomputed on the fly; e explicitly 0 outside the image = 'SAME' padding)
// -> blur -> sigma + per-tile partial sum. LDS ~21.9 KB.
// ---------------------------------------------------------------------------
__global__ __launch_bounds__(256) void k_sigma(const float* __restrict__ x,
                                               const float* __restrict__ kw,
                                               const float* __restrict__ lm,
                                               float* __restrict__ sg,
                                               float* __restrict__ psums) {
    __shared__ float et[RG * RS];
    __shared__ float wsum[4];
    const int tx = threadIdx.x, ty = threadIdx.y;
    const int tid = ty * 16 + tx;
    const int x0 = blockIdx.x * TILE, y0 = blockIdx.y * TILE;
    const float4* x4 = (const float4*)(x + (size_t)blockIdx.z * HW * 3);
    const float* lmb = lm + (size_t)blockIdx.z * HW;

    for (int i = tid; i < NQ; i += 256) {
        int r = i / 18, q = i - r * 18;
        int gy = y0 + r - 4, gx = x0 + 4 * q - 4;
        float4 e = make_float4(0.f, 0.f, 0.f, 0.f);
        if (gy >= 0 && gy < HH && gx >= 0 && gx < WW) {
            int go = (gy * WW + gx) >> 2;
            float4 a = x4[3 * go + 0];
            float4 b = x4[3 * go + 1];
            float4 c = x4[3 * go + 2];
            float4 l = *(const float4*)(lmb + (size_t)gy * WW + gx);
            const float t = 1.f / 3.f;
            float4 m, qq;
            m.x = (a.x + a.y + a.z) * t;  qq.x = (a.x * a.x + a.y * a.y + a.z * a.z) * t;
            m.y = (a.w + b.x + b.y) * t;  qq.y = (a.w * a.w + b.x * b.x + b.y * b.y) * t;
            m.z = (b.z + b.w + c.x) * t;  qq.z = (b.z * b.z + b.w * b.w + c.x * c.x) * t;
            m.w = (c.y + c.z + c.w) * t;  qq.w = (c.y * c.y + c.z * c.z + c.w * c.w) * t;
            e.x = fmaxf(qq.x - l.x * (2.f * m.x - l.x), 0.f);
            e.y = fmaxf(qq.y - l.y * (2.f * m.y - l.y), 0.f);
            e.z = fmaxf(qq.z - l.z * (2.f * m.z - l.z), 0.f);
            e.w = fmaxf(qq.w - l.w * (2.f * m.w - l.w), 0.f);
        }
        *(float4*)&et[r * RS + 4 * q] = e;
    }
    __syncthreads();

    const float4* t4 = (const float4*)et;
    float acc[4][4] = {};
    BLUR_4x4(acc, t4, kw, tx, ty);

    float s = 0.f;
    float* dp = sg + (size_t)blockIdx.z * HW + (size_t)(y0 + 4 * ty) * WW + x0 + 4 * tx;
#pragma unroll
    for (int my = 0; my < 4; ++my) {
        float4 o;
        o.x = sqrtf(fmaxf(acc[my][0], 0.f));
        o.y = sqrtf(fmaxf(acc[my][1], 0.f));
        o.z = sqrtf(fmaxf(acc[my][2], 0.f));
        o.w = sqrtf(fmaxf(acc[my][3], 0.f));
        *(float4*)(dp + my * WW) = o;
        s += o.x + o.y + o.z + o.w;
    }
#pragma unroll
    for (int off = 32; off > 0; off >>= 1) s += __shfl_down(s, off);
    if ((tid & 63) == 0) wsum[tid >> 6] = s;
    __syncthreads();
    if (tid == 0)
        psums[blockIdx.z * 64 + blockIdx.y * 8 + blockIdx.x] =
            wsum[0] + wsum[1] + wsum[2] + wsum[3];
}

// ---------------------------------------------------------------------------
// KC: out = (x - lm) / max(mean_sigma_b, sigma); in-block psums reduction.
// ---------------------------------------------------------------------------
__global__ __launch_bounds__(256) void k_norm(const float4* __restrict__ x4,
                                              const float4* __restrict__ lm4,
                                              const float4* __restrict__ sg4,
                                              const float* __restrict__ psums,
                                              float4* __restrict__ out4) {
    __shared__ float msh;
    int g = blockIdx.x * 256 + threadIdx.x;
    int b = g >> 16;                                  // g / (HW/4); uniform per block
    float s = 0.f;
    if (threadIdx.x < 64) s = psums[b * 64 + threadIdx.x];
#pragma unroll
    for (int off = 32; off > 0; off >>= 1) s += __shfl_down(s, off);
    if (threadIdx.x == 0) msh = s * (1.f / (float)HW);
    __syncthreads();
    float ms = msh;

    float4 l = lm4[g];
    float4 sv = sg4[g];
    float i0 = 1.f / fmaxf(ms, sv.x);
    float i1 = 1.f / fmaxf(ms, sv.y);
    float i2 = 1.f / fmaxf(ms, sv.z);
    float i3 = 1.f / fmaxf(ms, sv.w);
    float4 a = x4[3 * g + 0];
    float4 bb = x4[3 * g + 1];
    float4 c = x4[3 * g + 2];
    float4 o0, o1, o2;
    o0.x = (a.x - l.x) * i0;  o0.y = (a.y - l.x) * i0;  o0.z = (a.z - l.x) * i0;
    o0.w = (a.w - l.y) * i1;  o1.x = (bb.x - l.y) * i1; o1.y = (bb.y - l.y) * i1;
    o1.z = (bb.z - l.z) * i2; o1.w = (bb.w - l.z) * i2; o2.x = (c.x - l.z) * i2;
    o2.y = (c.y - l.w) * i3;  o2.z = (c.z - l.w) * i3;  o2.w = (c.w - l.w) * i3;
    out4[3 * g + 0] = o0;
    out4[3 * g + 1] = o1;
    out4[3 * g + 2] = o2;
}

extern "C" void kernel_launch(void* const* d_in, const int* in_sizes, int n_in,
                              void* d_out, int out_size, void* d_ws, size_t ws_size,
                              hipStream_t stream) {
    const float* x = (const float*)d_in[0];
    const float* kw = (const float*)d_in[1];
    float* out = (float*)d_out;
    float* wsp = (float*)d_ws;
    float* lmb = wsp;                                 // NPIX floats
    float* sgb = wsp + (size_t)NPIX;                  // NPIX floats
    float* ps  = wsp + 2 * (size_t)NPIX;              // 2048 floats

    dim3 blk(16, 16);
    dim3 grd(WW / TILE, HH / TILE, BB);
    k_lm<<<grd, blk, 0, stream>>>(x, kw, lmb);
    k_sigma<<<grd, blk, 0, stream>>>(x, kw, lmb, sgb, ps);

    k_norm<<<NPIX / 4 / 256, 256, 0, stream>>>((const float4*)x, (const float4*)lmb,
                                               (const float4*)sgb, ps, (float4*)out);
}